// Round 3
// baseline (699.655 us; speedup 1.0000x reference)
//
#include <hip/hip_runtime.h>
#include <hip/hip_bf16.h>

// Problem constants
#define B_    32
#define N_    32
#define E_    128
#define CIN_  64
#define COUT_ 128
#define H_    128
#define W_    128

using bf16x8 = __attribute__((ext_vector_type(8))) short;
using f32x4  = __attribute__((ext_vector_type(4))) float;

static __device__ __forceinline__ unsigned short f2bf(float f) {
  union { float f; unsigned u; } v; v.f = f;
  unsigned r = v.u + 0x7FFFu + ((v.u >> 16) & 1u);   // RNE
  return (unsigned short)(r >> 16);
}

// async global->LDS, 16B per lane (global_load_lds_dwordx4)
static __device__ __forceinline__ void gl2lds16(const void* g, void* l) {
  __builtin_amdgcn_global_load_lds(
      (const __attribute__((address_space(1))) unsigned int*)g,
      (__attribute__((address_space(3))) unsigned int*)l, 16, 0, 0);
}

// ---------------------------------------------------------------------------
// prep_kernel: one launch doing 4 independent jobs, selected by blockIdx.x
//   [0,4096)    : NCHW fp32 -> padded NHWC bf16 transpose (one (b,y) row each)
//   [4096,4160) : zero the y-pad rows (yp = 0 and 129 for each b)
//   [4160,4448) : pack conv_w [COUT][CIN][3][3] -> Wp [tap][cout][ci] bf16
//   [4448,5216) : QKV  qkv[mat][b][n][k] = cat(node,goal) @ W
// R3: smem shrunk 33280 -> 16896 B (QKV stages node_embeds only; the
// goal-half of the dot is n-independent -> computed once per thread from
// L1-broadcast loads). <32KB LDS doubles resident blocks/CU (occupancy fix).
// ---------------------------------------------------------------------------
__global__ __launch_bounds__(256) void prep_kernel(
    const float* __restrict__ state, const float* __restrict__ node_embeds,
    const float* __restrict__ goal_embed, const float* __restrict__ conv_w,
    const float* __restrict__ wQ, const float* __restrict__ wK,
    const float* __restrict__ wV,
    short* __restrict__ nhwc, short* __restrict__ Wp, float* __restrict__ qkv) {
  __shared__ __align__(16) unsigned char smem[16896];
  int bid = blockIdx.x, tid = threadIdx.x;

  if (bid < 4096) {
    // ---------- transpose one (b,y) row ----------
    int b = bid >> 7, y = bid & 127;
    unsigned* lds = (unsigned*)smem;              // [128 cells][32 dwords] = 16384 B
    int cp = tid >> 3;                            // ci pair: ci = 2cp, 2cp+1
    int xo = (tid & 7) << 4;                      // x offset, 16 x per thread
    const float* r0 = state + (((b * 64 + 2 * cp) * 128 + y) * 128) + xo;
    const float* r1 = r0 + 16384;                 // next ci row (+64KB)
    float4 a0[4], a1[4];
#pragma unroll
    for (int j = 0; j < 4; ++j) { a0[j] = *(const float4*)(r0 + 4 * j); a1[j] = *(const float4*)(r1 + 4 * j); }
    int k16 = cp >> 2;
    const float* f0 = (const float*)a0;
    const float* f1 = (const float*)a1;
#pragma unroll
    for (int jj = 0; jj < 16; ++jj) {
      int x = xo + jj;
      unsigned pk = (unsigned)f2bf(f0[jj]) | ((unsigned)f2bf(f1[jj]) << 16);
      lds[x * 32 + (((k16 + x + 1) & 7) << 2) + (cp & 3)] = pk;
    }
    __syncthreads();
    // coalesced store: thread t -> cell = t>>1, half = t&1 (64B each)
    int cell = tid >> 1, h = tid & 1;
    unsigned* rowbase = (unsigned*)nhwc + (size_t)((b * 130 + y + 1) * 136) * 32;
    unsigned* dst = rowbase + (cell + 1) * 32 + h * 16;
    unsigned* src = lds + cell * 32 + h * 16;
#pragma unroll
    for (int k = 0; k < 4; ++k) *(uint4*)(dst + 4 * k) = *(uint4*)(src + 4 * k);
    // zero x-pads of this row: cell 0 (32 dw) + cells 129..135 (224 dw)
    if (tid < 32) rowbase[tid] = 0;
    else rowbase[129 * 32 + (tid - 32)] = 0;
  } else if (bid < 4160) {
    // ---------- zero y-pad rows ----------
    int idx = bid - 4096;
    int b = idx >> 1, yp = (idx & 1) ? 129 : 0;
    unsigned* rowbase = (unsigned*)nhwc + (size_t)((b * 130 + yp) * 136) * 32;
    for (int k = tid; k < 136 * 32; k += 256) rowbase[k] = 0;
  } else if (bid < 4448) {
    // ---------- pack weights ----------
    int idx = (bid - 4160) * 256 + tid;
    if (idx < COUT_ * CIN_ * 9) {
      int cout = idx / (CIN_ * 9);
      int rem  = idx % (CIN_ * 9);
      int ci   = rem / 9;
      int tap  = rem % 9;
      Wp[(tap * COUT_ + cout) * CIN_ + ci] = (short)f2bf(conv_w[idx]);
    }
  } else {
    // ---------- QKV ----------
    int idx = bid - 4448;
    int kg = idx & 7;
    int r  = idx >> 3;
    int b  = r / 3;
    int mat = r - b * 3;
    const float* W = (mat == 0) ? wQ : (mat == 1) ? wK : wV;
    float (*x)[132] = (float(*)[132])smem;        // node rows only: 32*132*4 = 16896 B
    for (int e = tid; e < 4096; e += 256) x[e >> 7][e & 127] = node_embeds[e];
    __syncthreads();
    int k  = kg * 16 + (tid & 15);
    int n0 = tid >> 4, n1 = n0 + 16;
    const float* gb_ = goal_embed + b * 128;
    float a0 = 0.f, a1 = 0.f, s2 = 0.f;
    for (int f = 0; f < 128; f += 4) {
      float4 xv0 = *(const float4*)&x[n0][f];
      float4 xv1 = *(const float4*)&x[n1][f];
      float w0 = W[(f + 0) * 128 + k];
      float w1 = W[(f + 1) * 128 + k];
      float w2 = W[(f + 2) * 128 + k];
      float w3 = W[(f + 3) * 128 + k];
      a0 += xv0.x * w0 + xv0.y * w1 + xv0.z * w2 + xv0.w * w3;
      a1 += xv1.x * w0 + xv1.y * w1 + xv1.z * w2 + xv1.w * w3;
      // goal-half: n-independent (same row for every n) -> accumulate once
      float4 gv = *(const float4*)&gb_[f];
      float u0 = W[(128 + f) * 128 + k];
      float u1 = W[(129 + f) * 128 + k];
      float u2 = W[(130 + f) * 128 + k];
      float u3 = W[(131 + f) * 128 + k];
      s2 += gv.x * u0 + gv.y * u1 + gv.z * u2 + gv.w * u3;
    }
    a0 += s2; a1 += s2;
    int base = (mat * 32 + b) * 32;
    qkv[(base + n0) * 128 + k] = a0;
    qkv[(base + n1) * 128 + k] = a1;
  }
}

// ---------------------------------------------------------------------------
// scores + softmax + P@V -> atten[b][q][k].  grid 32 (b), block 256
// ---------------------------------------------------------------------------
__global__ void attn_kernel(const float* __restrict__ qkv, float* __restrict__ atten) {
  __shared__ float QS[32][132], KS[32][132], VS[32][132];
  __shared__ float S[32][33];
  int tid = threadIdx.x, b = blockIdx.x;
  const float* q0 = qkv + b * 4096;
  const float* k0 = qkv + 131072 + b * 4096;
  const float* v0 = qkv + 262144 + b * 4096;
  for (int e = tid; e < 4096; e += 256) {
    int n = e >> 7, k = e & 127;
    QS[n][k] = q0[e]; KS[n][k] = k0[e]; VS[n][k] = v0[e];
  }
  __syncthreads();
  for (int p = tid; p < 1024; p += 256) {
    int qi = p >> 5, ni = p & 31;
    float acc = 0.f;
    for (int k = 0; k < 128; k += 4) {
      float4 a = *(const float4*)&QS[qi][k];
      float4 c = *(const float4*)&KS[ni][k];
      acc += a.x * c.x + a.y * c.y + a.z * c.z + a.w * c.w;
    }
    S[qi][ni] = acc * 0.08838834764831845f;  // 1/sqrt(128)
  }
  __syncthreads();
  if (tid < 32) {
    float mx = -1e30f;
    for (int n = 0; n < 32; ++n) mx = fmaxf(mx, S[tid][n]);
    float sum = 0.f;
    for (int n = 0; n < 32; ++n) { float e = __expf(S[tid][n] - mx); S[tid][n] = e; sum += e; }
    float inv = 1.f / sum;
    for (int n = 0; n < 32; ++n) S[tid][n] *= inv;
  }
  __syncthreads();
  int qi = tid >> 3, ks = (tid & 7) * 16;
  float4 A0 = {0,0,0,0}, A1 = {0,0,0,0}, A2 = {0,0,0,0}, A3 = {0,0,0,0};
  for (int n = 0; n < 32; ++n) {
    float p = S[qi][n];
    float4 v_0 = *(const float4*)&VS[n][ks];
    float4 v_1 = *(const float4*)&VS[n][ks + 4];
    float4 v_2 = *(const float4*)&VS[n][ks + 8];
    float4 v_3 = *(const float4*)&VS[n][ks + 12];
    A0.x += p * v_0.x; A0.y += p * v_0.y; A0.z += p * v_0.z; A0.w += p * v_0.w;
    A1.x += p * v_1.x; A1.y += p * v_1.y; A1.z += p * v_1.z; A1.w += p * v_1.w;
    A2.x += p * v_2.x; A2.y += p * v_2.y; A2.z += p * v_2.z; A2.w += p * v_2.w;
    A3.x += p * v_3.x; A3.y += p * v_3.y; A3.z += p * v_3.z; A3.w += p * v_3.w;
  }
  float* op = atten + (b * 32 + qi) * 128 + ks;
  *(float4*)&op[0] = A0; *(float4*)&op[4] = A1; *(float4*)&op[8] = A2; *(float4*)&op[12] = A3;
}

// ---------------------------------------------------------------------------
// out_node[b][n][o] = fb[o] + sum_k atten[b][n][k] * fw[o][k]
// grid (32 n, 32 b), block 128
// ---------------------------------------------------------------------------
__global__ void final_kernel(const float* __restrict__ atten, const float* __restrict__ fw,
                             const float* __restrict__ fb, float* __restrict__ out_node) {
  __shared__ float ar[128];
  int tid = threadIdx.x;
  int n = blockIdx.x, b = blockIdx.y;
  ar[tid] = atten[(b * 32 + n) * 128 + tid];
  __syncthreads();
  const float* fr = fw + tid * 128;
  float acc = fb[tid];
  for (int k = 0; k < 128; k += 4) {
    float4 f = *(const float4*)&fr[k];
    acc += ar[k] * f.x + ar[k + 1] * f.y + ar[k + 2] * f.z + ar[k + 3] * f.w;
  }
  out_node[(b * 32 + n) * 128 + tid] = acc;
}

// ---------------------------------------------------------------------------
// Fused conv3x3 (bf16 implicit GEMM, MFMA 16x16x32) + gather-add epilogue
// Input: padded NHWC bf16, swizzled 16B chunks. Staging = pure global_load_lds.
// R3 retile for occupancy: 32-col x-tiles -> LDS 20480 B (<32K), grid
// (64 y, 4 x, 32 b) = 8192 blocks, acc[4][2], A-ring depth-1 (copy-free).
// Target: 4-5 resident blocks/CU (was ~2) so stage-drain / K-loop / store
// phases of different blocks overlap.
// C tile = 128 cout x 64 spatial (2 rows x 32 cols); K = 9 taps x 64 ci
// ---------------------------------------------------------------------------
#define XC2 40   // LDS cells per row (34 needed, 40 loaded = 5 x 1KB chunks)
__global__ __launch_bounds__(256, 4) void conv_kernel(
    const short* __restrict__ nhwc, const float* __restrict__ conv_b,
    const int* __restrict__ game_board, const int* __restrict__ char_to_node,
    const short* __restrict__ Wp, const float* __restrict__ out_node,
    float* __restrict__ out) {
  __shared__ __align__(16) short tile[4 * XC2 * 64];   // 20480 B
  int tid = threadIdx.x;
  int lane = tid & 63, wave = tid >> 6;
  int y0 = blockIdx.x * 2;
  int x0 = blockIdx.y * 32;
  int b  = blockIdx.z;

  // ---- stage: wave w loads LDS row w (padded y = y0+w), 5 chunks x 1KB ----
  {
    const short* grow = nhwc + (size_t)((b * 130 + y0 + wave) * 136 + x0) * 64;
    short* lrow = tile + wave * (XC2 * 64);
#pragma unroll
    for (int ch = 0; ch < 5; ++ch)
      gl2lds16(grow + ch * 512 + lane * 8, lrow + ch * 512 + lane * 8);
  }

  int q = lane >> 4, i = lane & 15;
  int mtset = (wave >> 1) * 4;   // m-tile base: waves {0,1}->couts 0..63, {2,3}->64..127
  int ty    = wave & 1;          // output row within tile
  int gy    = y0 + ty;

  // ---- hoisted epilogue gather indices (hide the dependent chain under stage) ----
  int nidx[2]; bool gval[2];
#pragma unroll
  for (int ntl = 0; ntl < 2; ++ntl) {
    int gx = x0 + ntl * 16 + i;
    int gb = game_board[(b * 128 + gy) * 128 + gx];
    gval[ntl] = (gb >= 0 && gb < 32);
    int nn = gval[ntl] ? char_to_node[gb] : 0;
    nidx[ntl] = nn < 0 ? 0 : (nn > 31 ? 31 : nn);
  }

  f32x4 acc[4][2];
#pragma unroll
  for (int m = 0; m < 4; ++m)
#pragma unroll
    for (int n = 0; n < 2; ++n) acc[m][n] = (f32x4){0.f, 0.f, 0.f, 0.f};

  // A-frags: Wp[t][cout][h*32 + q*8 + j], cout = (mtset+m)*16 + i
  // copy-free ring of 2, prefetch depth 1 (keeps VGPR ~100 for occupancy)
  const short* wbase = Wp + i * 64 + q * 8;
  bf16x8 aR[2][4];
#pragma unroll
  for (int m = 0; m < 4; ++m) aR[0][m] = *(const bf16x8*)(wbase + (mtset + m) * 1024);  // chunk 0

  __syncthreads();

#pragma unroll
  for (int chunk = 0; chunk < 18; ++chunk) {
    int t = chunk >> 1, h = chunk & 1;
    int kh = t / 3, kw = t - kh * 3;
    int row = ty + kh;
    bf16x8 bF[2];
#pragma unroll
    for (int ntl = 0; ntl < 2; ++ntl) {
      int c = ntl * 16 + i + kw;
      bF[ntl] = *(const bf16x8*)(tile + (row * XC2 + c) * 64 + (((h * 4 + q + c) & 7) << 3));
    }
    if (chunk < 17) {                       // prefetch next chunk's A-frags
      int c2 = chunk + 1;
      const short* wb2 = wbase + (c2 >> 1) * 8192 + (c2 & 1) * 32;
#pragma unroll
      for (int m = 0; m < 4; ++m) aR[c2 & 1][m] = *(const bf16x8*)(wb2 + (mtset + m) * 1024);
    }
#pragma unroll
    for (int m = 0; m < 4; ++m)
#pragma unroll
      for (int n = 0; n < 2; ++n)
        acc[m][n] = __builtin_amdgcn_mfma_f32_16x16x32_bf16(aR[chunk & 1][m], bF[n], acc[m][n], 0, 0, 0);
  }

  // ---- epilogue: bias + gather in-register, LDS transpose, float4 stores ----
  // Pass p handles couts [p*64, p*64+64): written by waves {2p, 2p+1}.
  // LDS float layout: idx = c'*68 + row*32 + x  (c' in [0,64), x in [0,32))
  //   write banks 2-way (free); reads float4 16B-aligned; 64*68*4 = 17408 B
  float* tbuf = (float*)tile;
#pragma unroll
  for (int p = 0; p < 2; ++p) {
    __syncthreads();   // pass 0: K-loop tile reads done; pass 1: pass-0 reads done
    if ((wave >> 1) == p) {
#pragma unroll
      for (int ntl = 0; ntl < 2; ++ntl) {
        const float* gn = out_node + (b * 32 + nidx[ntl]) * 128;
        bool valid = gval[ntl];
#pragma unroll
        for (int m = 0; m < 4; ++m) {
          int c0 = (mtset + m) * 16 + q * 4;          // global cout of reg 0
          float4 bias = *(const float4*)(conv_b + c0);
          float4 g = valid ? *(const float4*)(gn + c0) : make_float4(0.f, 0.f, 0.f, 0.f);
          f32x4 a = acc[m][ntl];
          int base = (m * 16 + q * 4) * 68 + ty * 32 + ntl * 16 + i;
          tbuf[base]       = a[0] + bias.x + g.x;
          tbuf[base + 68]  = a[1] + bias.y + g.y;
          tbuf[base + 136] = a[2] + bias.z + g.z;
          tbuf[base + 204] = a[3] + bias.w + g.w;
        }
      }
    }
    __syncthreads();
    // all 4 waves: read x-contiguous float4, store coalesced (8x128B lines/instr)
#pragma unroll
    for (int it = 0; it < 4; ++it) {
      int f  = tid + it * 256;
      int cp_ = f >> 4, rem = f & 15;
      int row = rem >> 3, xq = rem & 7;
      float4 v = *(const float4*)&tbuf[cp_ * 68 + row * 32 + xq * 4];
      int c = p * 64 + cp_;
      int addr = (b * 128 + c) * 16384 + (y0 + row) * 128 + x0 + xq * 4;
      *(float4*)&out[addr] = v;
    }
  }
}

// ---------------------------------------------------------------------------
extern "C" void kernel_launch(void* const* d_in, const int* in_sizes, int n_in,
                              void* d_out, int out_size, void* d_ws, size_t ws_size,
                              hipStream_t stream) {
  const int*   game_board   = (const int*)  d_in[0];
  const float* state        = (const float*)d_in[1];
  const float* node_embeds  = (const float*)d_in[2];
  const float* goal_embed   = (const float*)d_in[3];
  const int*   char_to_node = (const int*)  d_in[4];
  const float* conv_w       = (const float*)d_in[5];
  const float* conv_b       = (const float*)d_in[6];
  const float* wQ           = (const float*)d_in[7];
  const float* wK           = (const float*)d_in[8];
  const float* wV           = (const float*)d_in[9];
  const float* final_w      = (const float*)d_in[10];
  const float* final_b      = (const float*)d_in[11];
  float* out = (float*)d_out;

  char* ws = (char*)d_ws;
  short* Wp       = (short*)(ws);             // 147456 B   bf16 weights [9][128][64]
  float* qkv      = (float*)(ws + 147456);    // 1572864 B  [3][32][32][128] fp32
  float* atten    = (float*)(ws + 1720320);   // 524288 B   [32][32][128] fp32
  float* out_node = (float*)(ws + 2244608);   // 524288 B   [32][32][128] fp32
  short* nhwc     = (short*)(ws + 2768896);   // 72417280 B [32][130][136][64] bf16 padded+swizzled

  hipLaunchKernelGGL(prep_kernel, dim3(5216), dim3(256), 0, stream,
                     state, node_embeds, goal_embed, conv_w, wQ, wK, wV, nhwc, Wp, qkv);
  hipLaunchKernelGGL(attn_kernel, dim3(32), dim3(256), 0, stream, qkv, atten);
  hipLaunchKernelGGL(final_kernel, dim3(32, 32), dim3(128), 0, stream, atten, final_w, final_b, out_node);
  hipLaunchKernelGGL(conv_kernel, dim3(64, 4, 32), dim3(256), 0, stream,
                     nhwc, conv_b, game_board, char_to_node, Wp, out_node, out);
}

// Round 4
// 592.111 us; speedup vs baseline: 1.1816x; 1.1816x over previous
//
#include <hip/hip_runtime.h>
#include <hip/hip_bf16.h>

// Problem constants
#define B_    32
#define N_    32
#define E_    128
#define CIN_  64
#define COUT_ 128
#define H_    128
#define W_    128

using bf16x8 = __attribute__((ext_vector_type(8))) short;
using f32x4  = __attribute__((ext_vector_type(4))) float;

static __device__ __forceinline__ unsigned short f2bf(float f) {
  union { float f; unsigned u; } v; v.f = f;
  unsigned r = v.u + 0x7FFFu + ((v.u >> 16) & 1u);   // RNE
  return (unsigned short)(r >> 16);
}

// ---------------------------------------------------------------------------
// prep_kernel (R4: transpose + pad branches deleted — conv stages from state
// directly now). Two jobs:
//   [0,288)    : pack conv_w [COUT][CIN][3][3] -> Wp [tap][cout][ci] bf16
//   [288,1056) : QKV  qkv[mat][b][n][k] = cat(node,goal) @ W
//                (goal-half is n-independent -> single accumulator s2)
// ---------------------------------------------------------------------------
__global__ __launch_bounds__(256) void prep_kernel(
    const float* __restrict__ node_embeds, const float* __restrict__ goal_embed,
    const float* __restrict__ conv_w,
    const float* __restrict__ wQ, const float* __restrict__ wK,
    const float* __restrict__ wV,
    short* __restrict__ Wp, float* __restrict__ qkv) {
  __shared__ __align__(16) float xs[32][132];   // 16896 B
  int bid = blockIdx.x, tid = threadIdx.x;

  if (bid < 288) {
    // ---------- pack weights ----------
    int idx = bid * 256 + tid;
    if (idx < COUT_ * CIN_ * 9) {
      int cout = idx / (CIN_ * 9);
      int rem  = idx % (CIN_ * 9);
      int ci   = rem / 9;
      int tap  = rem % 9;
      Wp[(tap * COUT_ + cout) * CIN_ + ci] = (short)f2bf(conv_w[idx]);
    }
  } else {
    // ---------- QKV ----------
    int idx = bid - 288;
    int kg = idx & 7;
    int r  = idx >> 3;
    int b  = r / 3;
    int mat = r - b * 3;
    const float* W = (mat == 0) ? wQ : (mat == 1) ? wK : wV;
    for (int e = tid; e < 4096; e += 256) xs[e >> 7][e & 127] = node_embeds[e];
    __syncthreads();
    int k  = kg * 16 + (tid & 15);
    int n0 = tid >> 4, n1 = n0 + 16;
    const float* gb_ = goal_embed + b * 128;
    float a0 = 0.f, a1 = 0.f, s2 = 0.f;
    for (int f = 0; f < 128; f += 4) {
      float4 xv0 = *(const float4*)&xs[n0][f];
      float4 xv1 = *(const float4*)&xs[n1][f];
      float w0 = W[(f + 0) * 128 + k];
      float w1 = W[(f + 1) * 128 + k];
      float w2 = W[(f + 2) * 128 + k];
      float w3 = W[(f + 3) * 128 + k];
      a0 += xv0.x * w0 + xv0.y * w1 + xv0.z * w2 + xv0.w * w3;
      a1 += xv1.x * w0 + xv1.y * w1 + xv1.z * w2 + xv1.w * w3;
      // goal-half: n-independent (same row for every n) -> accumulate once
      float4 gv = *(const float4*)&gb_[f];
      float u0 = W[(128 + f) * 128 + k];
      float u1 = W[(129 + f) * 128 + k];
      float u2 = W[(130 + f) * 128 + k];
      float u3 = W[(131 + f) * 128 + k];
      s2 += gv.x * u0 + gv.y * u1 + gv.z * u2 + gv.w * u3;
    }
    a0 += s2; a1 += s2;
    int base = (mat * 32 + b) * 32;
    qkv[(base + n0) * 128 + k] = a0;
    qkv[(base + n1) * 128 + k] = a1;
  }
}

// ---------------------------------------------------------------------------
// scores + softmax + P@V -> atten[b][q][k].  grid 32 (b), block 256
// ---------------------------------------------------------------------------
__global__ void attn_kernel(const float* __restrict__ qkv, float* __restrict__ atten) {
  __shared__ float QS[32][132], KS[32][132], VS[32][132];
  __shared__ float S[32][33];
  int tid = threadIdx.x, b = blockIdx.x;
  const float* q0 = qkv + b * 4096;
  const float* k0 = qkv + 131072 + b * 4096;
  const float* v0 = qkv + 262144 + b * 4096;
  for (int e = tid; e < 4096; e += 256) {
    int n = e >> 7, k = e & 127;
    QS[n][k] = q0[e]; KS[n][k] = k0[e]; VS[n][k] = v0[e];
  }
  __syncthreads();
  for (int p = tid; p < 1024; p += 256) {
    int qi = p >> 5, ni = p & 31;
    float acc = 0.f;
    for (int k = 0; k < 128; k += 4) {
      float4 a = *(const float4*)&QS[qi][k];
      float4 c = *(const float4*)&KS[ni][k];
      acc += a.x * c.x + a.y * c.y + a.z * c.z + a.w * c.w;
    }
    S[qi][ni] = acc * 0.08838834764831845f;  // 1/sqrt(128)
  }
  __syncthreads();
  if (tid < 32) {
    float mx = -1e30f;
    for (int n = 0; n < 32; ++n) mx = fmaxf(mx, S[tid][n]);
    float sum = 0.f;
    for (int n = 0; n < 32; ++n) { float e = __expf(S[tid][n] - mx); S[tid][n] = e; sum += e; }
    float inv = 1.f / sum;
    for (int n = 0; n < 32; ++n) S[tid][n] *= inv;
  }
  __syncthreads();
  int qi = tid >> 3, ks = (tid & 7) * 16;
  float4 A0 = {0,0,0,0}, A1 = {0,0,0,0}, A2 = {0,0,0,0}, A3 = {0,0,0,0};
  for (int n = 0; n < 32; ++n) {
    float p = S[qi][n];
    float4 v_0 = *(const float4*)&VS[n][ks];
    float4 v_1 = *(const float4*)&VS[n][ks + 4];
    float4 v_2 = *(const float4*)&VS[n][ks + 8];
    float4 v_3 = *(const float4*)&VS[n][ks + 12];
    A0.x += p * v_0.x; A0.y += p * v_0.y; A0.z += p * v_0.z; A0.w += p * v_0.w;
    A1.x += p * v_1.x; A1.y += p * v_1.y; A1.z += p * v_1.z; A1.w += p * v_1.w;
    A2.x += p * v_2.x; A2.y += p * v_2.y; A2.z += p * v_2.z; A2.w += p * v_2.w;
    A3.x += p * v_3.x; A3.y += p * v_3.y; A3.z += p * v_3.z; A3.w += p * v_3.w;
  }
  float* op = atten + (b * 32 + qi) * 128 + ks;
  *(float4*)&op[0] = A0; *(float4*)&op[4] = A1; *(float4*)&op[8] = A2; *(float4*)&op[12] = A3;
}

// ---------------------------------------------------------------------------
// out_node[b][n][o] = fb[o] + sum_k atten[b][n][k] * fw[o][k]
// grid (32 n, 32 b), block 128
// ---------------------------------------------------------------------------
__global__ void final_kernel(const float* __restrict__ atten, const float* __restrict__ fw,
                             const float* __restrict__ fb, float* __restrict__ out_node) {
  __shared__ float ar[128];
  int tid = threadIdx.x;
  int n = blockIdx.x, b = blockIdx.y;
  ar[tid] = atten[(b * 32 + n) * 128 + tid];
  __syncthreads();
  const float* fr = fw + tid * 128;
  float acc = fb[tid];
  for (int k = 0; k < 128; k += 4) {
    float4 f = *(const float4*)&fr[k];
    acc += ar[k] * f.x + ar[k + 1] * f.y + ar[k + 2] * f.z + ar[k + 3] * f.w;
  }
  out_node[(b * 32 + n) * 128 + tid] = acc;
}

// ---------------------------------------------------------------------------
// Fused transpose + conv3x3 (bf16 implicit GEMM, MFMA 16x16x32) + gather-add.
// R4: the nhwc intermediate is GONE. Stage reads NCHW fp32 state directly,
// converts via v_cvt_pk_bf16_f32, ds_writes into the rotated [row][cell][ci]
// layout (tile-relative rotation ((ci>>3)+cell)&7, dword (ci>>1)&3).
// K-loop + epilogue are the proven R2 structure (246 us config).
// grid (64 ytiles, 2 xtiles, 32 b), block 256 (4 waves)
// C tile = 128 cout x 128 spatial (2 rows x 64 cols); K = 9 taps x 64 ci
// cell c holds input column x = x0+c-1 (c in [0,66)); row r holds y = y0+r-1.
// ---------------------------------------------------------------------------
#define XC 72
__global__ __launch_bounds__(256) void conv_kernel(
    const float* __restrict__ state, const float* __restrict__ conv_b,
    const int* __restrict__ game_board, const int* __restrict__ char_to_node,
    const short* __restrict__ Wp, const float* __restrict__ out_node,
    float* __restrict__ out) {
  __shared__ __align__(16) short tile[4 * XC * 64];   // 36864 B
  int tid = threadIdx.x;
  int lane = tid & 63, wave = tid >> 6;
  int y0 = blockIdx.x * 2;
  int x0 = blockIdx.y * 64;
  int b  = blockIdx.z;

  unsigned* lds32 = (unsigned*)tile;

  // ---- stage: NCHW fp32 -> LDS bf16, transpose + rotate in one hop ----
  {
    int cp  = tid >> 3;                 // ci pair: ci = 2cp, 2cp+1
    int xo  = (tid & 7) << 3;           // 8 interior x per thread
    int k16 = cp >> 2;
    const float* sbase = state + (size_t)(b * 64 + 2 * cp) * 16384;
#pragma unroll
    for (int r = 0; r < 4; ++r) {
      int y = y0 + r - 1;
      bool yv = (unsigned)y < 128u;
      float e0[8], e1[8];
      if (yv) {
        const float* p0 = sbase + y * 128 + x0 + xo;
        const float* p1 = p0 + 16384;
        *(float4*)&e0[0] = *(const float4*)p0;
        *(float4*)&e0[4] = *(const float4*)(p0 + 4);
        *(float4*)&e1[0] = *(const float4*)p1;
        *(float4*)&e1[4] = *(const float4*)(p1 + 4);
      } else {
#pragma unroll
        for (int j = 0; j < 8; ++j) { e0[j] = 0.f; e1[j] = 0.f; }
      }
#pragma unroll
      for (int j = 0; j < 8; ++j) {
        int c = xo + j + 1;             // interior cells 1..64
        unsigned pk;
        asm("v_cvt_pk_bf16_f32 %0, %1, %2" : "=v"(pk) : "v"(e0[j]), "v"(e1[j]));
        lds32[((r * XC + c) << 5) + (((k16 + c) & 7) << 2) + (cp & 3)] = pk;
      }
    }
    // halo cells 0 and 65: one dword per thread (2 sides x 4 rows x 32 cp)
    int side = tid >> 7;
    int rem  = tid & 127;
    int r2   = rem >> 5, cq = rem & 31;
    int c    = side ? 65 : 0;
    int x    = x0 + (side ? 64 : -1);
    int y    = y0 + r2 - 1;
    float h0 = 0.f, h1 = 0.f;
    if ((unsigned)x < 128u && (unsigned)y < 128u) {
      const float* p = state + (size_t)(b * 64 + 2 * cq) * 16384 + y * 128 + x;
      h0 = p[0]; h1 = p[16384];
    }
    unsigned pk;
    asm("v_cvt_pk_bf16_f32 %0, %1, %2" : "=v"(pk) : "v"(h0), "v"(h1));
    lds32[((r2 * XC + c) << 5) + ((((cq >> 2) + c) & 7) << 2) + (cq & 3)] = pk;
  }

  int q = lane >> 4, i = lane & 15;
  int mtset = (wave >> 1) * 4;   // m-tile base: waves {0,1}->couts 0..63, {2,3}->64..127
  int ty    = wave & 1;          // output row within tile
  int gy    = y0 + ty;

  // ---- hoisted epilogue gather indices (hide the chain under stage drain) ----
  int nidx[4]; bool gval[4];
#pragma unroll
  for (int ntl = 0; ntl < 4; ++ntl) {
    int gx = x0 + ntl * 16 + i;
    int gb = game_board[(b * 128 + gy) * 128 + gx];
    gval[ntl] = (gb >= 0 && gb < 32);
    int nn = gval[ntl] ? char_to_node[gb] : 0;
    nidx[ntl] = nn < 0 ? 0 : (nn > 31 ? 31 : nn);
  }

  f32x4 acc[4][4];
#pragma unroll
  for (int m = 0; m < 4; ++m)
#pragma unroll
    for (int n = 0; n < 4; ++n) acc[m][n] = (f32x4){0.f, 0.f, 0.f, 0.f};

  // A-frags: Wp[t][cout][h*32 + q*8 + j], cout = (mtset+m)*16 + i
  // ring of 3 sets, statically indexed under full unroll; prefetch depth 2
  const short* wbase = Wp + i * 64 + q * 8;
  bf16x8 aR[3][4];
#pragma unroll
  for (int m = 0; m < 4; ++m) aR[0][m] = *(const bf16x8*)(wbase + (mtset + m) * 1024);
#pragma unroll
  for (int m = 0; m < 4; ++m) aR[1][m] = *(const bf16x8*)(wbase + 32 + (mtset + m) * 1024);

  __syncthreads();

#pragma unroll
  for (int chunk = 0; chunk < 18; ++chunk) {
    int t = chunk >> 1, h = chunk & 1;
    int kh = t / 3, kw = t - kh * 3;
    int row = ty + kh;
    bf16x8 bF[4];
#pragma unroll
    for (int ntl = 0; ntl < 4; ++ntl) {
      int c = ntl * 16 + i + kw;
      bF[ntl] = *(const bf16x8*)(tile + (row * XC + c) * 64 + (((h * 4 + q + c) & 7) << 3));
    }
    if (chunk < 16) {                       // prefetch A-frags two chunks ahead
      int c2 = chunk + 2;
      const short* wb2 = wbase + (c2 >> 1) * 8192 + (c2 & 1) * 32;
#pragma unroll
      for (int m = 0; m < 4; ++m) aR[(chunk + 2) % 3][m] = *(const bf16x8*)(wb2 + (mtset + m) * 1024);
    }
#pragma unroll
    for (int m = 0; m < 4; ++m)
#pragma unroll
      for (int n = 0; n < 4; ++n)
        acc[m][n] = __builtin_amdgcn_mfma_f32_16x16x32_bf16(aR[chunk % 3][m], bF[n], acc[m][n], 0, 0, 0);
  }

  // ---- epilogue: bias + gather in-register, LDS transpose, float4 stores ----
  // Pass p handles couts [p*64, p*64+64): written by waves {2p, 2p+1}.
  // LDS float layout: idx = c'*132 + row*64 + x  (2-way banking, free)
  float* tbuf = (float*)tile;
#pragma unroll
  for (int p = 0; p < 2; ++p) {
    __syncthreads();   // pass 0: K-loop tile reads done; pass 1: pass-0 reads done
    if ((wave >> 1) == p) {
#pragma unroll
      for (int ntl = 0; ntl < 4; ++ntl) {
        const float* gn = out_node + (b * 32 + nidx[ntl]) * 128;
        bool valid = gval[ntl];
#pragma unroll
        for (int m = 0; m < 4; ++m) {
          int c0 = (mtset + m) * 16 + q * 4;          // global cout of reg 0
          float4 bias = *(const float4*)(conv_b + c0);
          float4 g = valid ? *(const float4*)(gn + c0) : make_float4(0.f, 0.f, 0.f, 0.f);
          f32x4 a = acc[m][ntl];
          int base = (m * 16 + q * 4) * 132 + ty * 64 + ntl * 16 + i;
          tbuf[base]       = a[0] + bias.x + g.x;
          tbuf[base + 132] = a[1] + bias.y + g.y;
          tbuf[base + 264] = a[2] + bias.z + g.z;
          tbuf[base + 396] = a[3] + bias.w + g.w;
        }
      }
    }
    __syncthreads();
    // all 4 waves: read x-contiguous float4, store coalesced
#pragma unroll
    for (int it = 0; it < 8; ++it) {
      int f  = tid + it * 256;
      int cp_ = f >> 5, rem = f & 31;
      int row = rem >> 4, xq = rem & 15;
      float4 v = *(const float4*)&tbuf[cp_ * 132 + row * 64 + xq * 4];
      int c = p * 64 + cp_;
      int addr = (b * 128 + c) * 16384 + (y0 + row) * 128 + x0 + xq * 4;
      *(float4*)&out[addr] = v;
    }
  }
}

// ---------------------------------------------------------------------------
extern "C" void kernel_launch(void* const* d_in, const int* in_sizes, int n_in,
                              void* d_out, int out_size, void* d_ws, size_t ws_size,
                              hipStream_t stream) {
  const int*   game_board   = (const int*)  d_in[0];
  const float* state        = (const float*)d_in[1];
  const float* node_embeds  = (const float*)d_in[2];
  const float* goal_embed   = (const float*)d_in[3];
  const int*   char_to_node = (const int*)  d_in[4];
  const float* conv_w       = (const float*)d_in[5];
  const float* conv_b       = (const float*)d_in[6];
  const float* wQ           = (const float*)d_in[7];
  const float* wK           = (const float*)d_in[8];
  const float* wV           = (const float*)d_in[9];
  const float* final_w      = (const float*)d_in[10];
  const float* final_b      = (const float*)d_in[11];
  float* out = (float*)d_out;

  char* ws = (char*)d_ws;
  short* Wp       = (short*)(ws);             // 147456 B   bf16 weights [9][128][64]
  float* qkv      = (float*)(ws + 147456);    // 1572864 B  [3][32][32][128] fp32
  float* atten    = (float*)(ws + 1720320);   // 524288 B   [32][32][128] fp32
  float* out_node = (float*)(ws + 2244608);   // 524288 B   [32][32][128] fp32

  hipLaunchKernelGGL(prep_kernel, dim3(1056), dim3(256), 0, stream,
                     node_embeds, goal_embed, conv_w, wQ, wK, wV, Wp, qkv);
  hipLaunchKernelGGL(attn_kernel, dim3(32), dim3(256), 0, stream, qkv, atten);
  hipLaunchKernelGGL(final_kernel, dim3(32, 32), dim3(128), 0, stream, atten, final_w, final_b, out_node);
  hipLaunchKernelGGL(conv_kernel, dim3(64, 2, 32), dim3(256), 0, stream,
                     state, conv_b, game_board, char_to_node, Wp, out_node, out);
}